// Round 7
// baseline (174.069 us; speedup 1.0000x reference)
//
#include <hip/hip_runtime.h>
#include <stdint.h>

// GCN layer via linearity of mean:
//   Y[N,512] = bf16(vf) @ [W | B]   (one bf16 GEMM, K=256)
//   out[n]   = relu(mean_k Y[nbr[n,k], 0:256] + Y[n, 256:512])
// GEMM structure: B-panel (128 cols x 256 k = 64 KB) staged ONCE per block,
// A streamed 8 KB/k-step via global_load_lds; 80 KB LDS -> 2 blocks/CU.

#define N_V   50000
#define KNB   16
#define D_F   256
#define H_F   256
#define HK2   512            // Y columns
#define NPAD  50048          // N rounded up to 128

typedef __bf16 bf16x8 __attribute__((ext_vector_type(8)));
typedef float  f32x4  __attribute__((ext_vector_type(4)));
typedef float  f32x8  __attribute__((ext_vector_type(8)));
typedef unsigned short ushort8 __attribute__((ext_vector_type(8)));

static __device__ __forceinline__ unsigned short f2bf(float f) {
    union { float f; unsigned u; } v; v.f = f;
    unsigned u = v.u;
    u += 0x7fffu + ((u >> 16) & 1u);   // round-to-nearest-even
    return (unsigned short)(u >> 16);
}
static __device__ __forceinline__ float bf2f(unsigned short u) {
    union { unsigned u; float f; } v; v.u = ((unsigned)u) << 16; return v.f;
}
static __device__ __forceinline__ void load16(const void* g, void* l) {
    __builtin_amdgcn_global_load_lds(
        (__attribute__((address_space(1))) void*)g,
        (__attribute__((address_space(3))) void*)l, 16, 0, 0);
}

// ---------------- kernel 1: vf fp32 -> vfb bf16 (pad rows zeroed) ---------
__global__ __launch_bounds__(256) void vf_convert(
    const float* __restrict__ vf, unsigned short* __restrict__ vfb) {
    const int total = NPAD * (D_F / 8);            // 16-B chunks
    for (int c = blockIdx.x * 256 + threadIdx.x; c < total; c += gridDim.x * 256) {
        int n = c >> 5;
        int off = (c & 31) * 8;
        ushort8 o;
        if (n < N_V) {
            const float4 a = *(const float4*)(vf + (size_t)n * D_F + off);
            const float4 b = *(const float4*)(vf + (size_t)n * D_F + off + 4);
            o[0]=f2bf(a.x); o[1]=f2bf(a.y); o[2]=f2bf(a.z); o[3]=f2bf(a.w);
            o[4]=f2bf(b.x); o[5]=f2bf(b.y); o[6]=f2bf(b.z); o[7]=f2bf(b.w);
        } else {
            o = (ushort8)(0);
        }
        *(ushort8*)(vfb + (size_t)n * D_F + off) = o;
    }
}

// ---------------- kernel 2: W,B -> bf16 transposed WBt[512 h][256 k] ------
__global__ __launch_bounds__(256) void wbt_convert(
    const float* __restrict__ W, const float* __restrict__ Bm,
    unsigned short* __restrict__ WBt) {
    __shared__ unsigned short t[32][33];
    const int k0 = blockIdx.x * 32;                // 0..224
    const int h0 = blockIdx.y * 32;                // 0..480 (h<256:W, else B)
    const int tid = threadIdx.x;
    {
        int r  = tid >> 3;                         // k 0..31
        int c4 = (tid & 7) * 4;                    // h 0..28
        const float* src = (h0 < 256)
            ? (W  + (size_t)(k0 + r) * H_F + h0 + c4)
            : (Bm + (size_t)(k0 + r) * H_F + (h0 - 256) + c4);
        float4 v = *(const float4*)src;
        t[r][c4 + 0] = f2bf(v.x); t[r][c4 + 1] = f2bf(v.y);
        t[r][c4 + 2] = f2bf(v.z); t[r][c4 + 3] = f2bf(v.w);
    }
    __syncthreads();
    {
        int hh  = tid >> 3;
        int kk4 = (tid & 7) * 4;
        ushort4 o;
        o.x = t[kk4 + 0][hh]; o.y = t[kk4 + 1][hh];
        o.z = t[kk4 + 2][hh]; o.w = t[kk4 + 3][hh];
        *(ushort4*)(WBt + (size_t)(h0 + hh) * D_F + k0 + kk4) = o;
    }
}

// ---------------- kernel 3: Y = vfb @ WBt^T, 128x128 tile -----------------
// B-panel [128 n][256 k] staged once, swizzle ((r&7)<<4) on 512-B rows.
// A [128 m][32 k] double-buffered (8 KB/buf), swizzle ((r&3)<<4) on 64-B rows.
// 8 waves: wm=wave&3 (32 rows), wn=wave>>2 (64 cols). 80 KB LDS, 2 blk/CU.
__global__ __launch_bounds__(512, 4) void gemm_y(
    const unsigned short* __restrict__ vfb,
    const unsigned short* __restrict__ WBt,
    unsigned short* __restrict__ Y) {
    __shared__ char Bp[65536];
    __shared__ char Ap[2][8192];
    const int bn = blockIdx.x * 128;
    const int bm = blockIdx.y * 128;
    const int tid = threadIdx.x;
    const int wave = tid >> 6, lane = tid & 63;
    const int wm = wave & 3, wn = wave >> 2;

    f32x4 acc[2][4];
    const f32x4 fzero = {0.f, 0.f, 0.f, 0.f};
#pragma unroll
    for (int i = 0; i < 2; ++i)
#pragma unroll
        for (int j = 0; j < 4; ++j) acc[i][j] = fzero;

    // ---- stage B panel once: 64 KB = 8 x load16 per thread
#pragma unroll
    for (int i = 0; i < 8; ++i) {
        unsigned P = i * 8192u + tid * 16u;        // physical (linear dest)
        unsigned r = P >> 9, pc = P & 511u;
        unsigned lc = pc ^ ((r & 7u) << 4);        // logical byte col
        load16((const char*)WBt + (size_t)(bn + r) * 512 + lc,
               Bp + i * 8192 + wave * 1024);
    }
    // ---- A staging: 8 KB = one load16 per thread (512 threads, rows 0..127)
    auto stageA = [&](int buf, int t) {
        unsigned P = tid * 16u;                    // 0..8191
        unsigned r = P >> 6, pc = P & 63u;         // r 0..127
        unsigned lc = pc ^ ((r & 3u) << 4);
        load16((const char*)vfb + (size_t)(bm + r) * 512 + t * 64 + lc,
               Ap[buf] + wave * 1024);
    };
    stageA(0, 0);
    __syncthreads();

    int cur = 0;
    for (int t = 0; t < 8; ++t) {
        if (t < 7) stageA(cur ^ 1, t + 1);
        bf16x8 af[2], bfr[4];
#pragma unroll
        for (int mf = 0; mf < 2; ++mf) {
            unsigned r = wm * 32u + mf * 16u + (lane & 15);
            unsigned c = ((unsigned)lane >> 4) << 4;
            af[mf] = *(const bf16x8*)(Ap[cur] + r * 64 + (c ^ ((r & 3u) << 4)));
        }
#pragma unroll
        for (int nf = 0; nf < 4; ++nf) {
            unsigned r = wn * 64u + nf * 16u + (lane & 15);
            unsigned c = t * 64u + (((unsigned)lane >> 4) << 4);
            bfr[nf] = *(const bf16x8*)(Bp + r * 512 + (c ^ ((r & 7u) << 4)));
        }
#pragma unroll
        for (int mf = 0; mf < 2; ++mf)
#pragma unroll
            for (int nf = 0; nf < 4; ++nf)
                acc[mf][nf] = __builtin_amdgcn_mfma_f32_16x16x32_bf16(
                    af[mf], bfr[nf], acc[mf][nf], 0, 0, 0);
        __syncthreads();               // next A buf ready (vmcnt drained)
        cur ^= 1;
    }

    // ---- epilogue: Y bf16 store (pad rows are zero inputs, harmless)
#pragma unroll
    for (int mf = 0; mf < 2; ++mf) {
        int row0 = bm + wm * 32 + mf * 16 + ((lane >> 4) << 2);
#pragma unroll
        for (int nf = 0; nf < 4; ++nf) {
            int col = bn + wn * 64 + nf * 16 + (lane & 15);
            f32x4 v = acc[mf][nf];
#pragma unroll
            for (int i = 0; i < 4; ++i)
                Y[(size_t)(row0 + i) * HK2 + col] = f2bf(v[i]);
        }
    }
}

// ---------------- kernel 4: gather + mean + add + relu, 2 verts/wave ------
__global__ __launch_bounds__(256) void gather_out(
    const unsigned short* __restrict__ Y, const int* __restrict__ nbr,
    const int* __restrict__ lens, float* __restrict__ out) {
    const int wave = threadIdx.x >> 6;
    const int lane = threadIdx.x & 63;
    const int half = lane >> 5, laneh = lane & 31;
    const int v = blockIdx.x * 8 + wave * 2 + half;   // 6250*8 == 50000 exact
    const int base = lane & 32;
    const int col = laneh * 8;

    const int len = lens[v];
    const int idx = nbr[(size_t)v * KNB + (laneh & 15)];
    const ushort8 y2 = *(const ushort8*)(Y + (size_t)v * HK2 + 256 + col);

    f32x8 acc = {0.f,0.f,0.f,0.f,0.f,0.f,0.f,0.f};
#define ROW_(j) (*(const ushort8*)(Y + (size_t)(j) * HK2 + col))
#define ACC_(r) { acc[0]+=bf2f(r[0]); acc[1]+=bf2f(r[1]); acc[2]+=bf2f(r[2]); \
                  acc[3]+=bf2f(r[3]); acc[4]+=bf2f(r[4]); acc[5]+=bf2f(r[5]); \
                  acc[6]+=bf2f(r[6]); acc[7]+=bf2f(r[7]); }
    int k = 0;
    for (; k + 4 <= len; k += 4) {
        int j0 = __shfl(idx, base + k),     j1 = __shfl(idx, base + k + 1);
        int j2 = __shfl(idx, base + k + 2), j3 = __shfl(idx, base + k + 3);
        ushort8 r0 = ROW_(j0), r1 = ROW_(j1), r2 = ROW_(j2), r3 = ROW_(j3);
        ACC_(r0); ACC_(r1); ACC_(r2); ACC_(r3);
    }
    for (; k < len; ++k) {
        int j = __shfl(idx, base + k);
        ushort8 r = ROW_(j);
        ACC_(r);
    }
#undef ROW_
#undef ACC_
    const float inv = 1.0f / (float)(len > 0 ? len : 1);
    float4 o0, o1;
    o0.x = fmaxf(fmaf(acc[0], inv, bf2f(y2[0])), 0.f);
    o0.y = fmaxf(fmaf(acc[1], inv, bf2f(y2[1])), 0.f);
    o0.z = fmaxf(fmaf(acc[2], inv, bf2f(y2[2])), 0.f);
    o0.w = fmaxf(fmaf(acc[3], inv, bf2f(y2[3])), 0.f);
    o1.x = fmaxf(fmaf(acc[4], inv, bf2f(y2[4])), 0.f);
    o1.y = fmaxf(fmaf(acc[5], inv, bf2f(y2[5])), 0.f);
    o1.z = fmaxf(fmaf(acc[6], inv, bf2f(y2[6])), 0.f);
    o1.w = fmaxf(fmaf(acc[7], inv, bf2f(y2[7])), 0.f);
    float* op = out + (size_t)v * H_F + col;
    *(float4*)op = o0;
    *(float4*)(op + 4) = o1;
}

extern "C" void kernel_launch(void* const* d_in, const int* in_sizes, int n_in,
                              void* d_out, int out_size, void* d_ws, size_t ws_size,
                              hipStream_t stream) {
    const float* vf   = (const float*)d_in[0];
    const int*   nbr  = (const int*)d_in[1];
    const int*   lens = (const int*)d_in[2];
    const float* W    = (const float*)d_in[3];
    const float* Bm   = (const float*)d_in[4];
    float* out = (float*)d_out;

    unsigned short* Y    = (unsigned short*)d_ws;                 // NPAD*512 bf16
    unsigned short* vfb  = Y + (size_t)NPAD * HK2;                // NPAD*256 bf16
    unsigned short* WBt  = vfb + (size_t)NPAD * D_F;              // 512*256 bf16

    hipLaunchKernelGGL(vf_convert, dim3(2048), dim3(256), 0, stream, vf, vfb);
    hipLaunchKernelGGL(wbt_convert, dim3(8, 16), dim3(256), 0, stream, W, Bm, WBt);
    hipLaunchKernelGGL(gemm_y, dim3(4, NPAD / 128), dim3(512), 0, stream,
                       vfb, WBt, Y);
    hipLaunchKernelGGL(gather_out, dim3(N_V / 8), dim3(256), 0, stream,
                       Y, nbr, lens, out);
}

// Round 9
// 173.641 us; speedup vs baseline: 1.0025x; 1.0025x over previous
//
#include <hip/hip_runtime.h>
#include <stdint.h>

// GCN layer via linearity of mean:
//   Y[N,512] = bf16(vf) @ [W | B]   (one bf16 GEMM, K=256)
//   out[n]   = relu(mean_k Y[nbr[n,k], 0:256] + Y[n, 256:512])
// GEMM: B-panel (128 cols x 256 k = 64 KB) resident per block via
// global_load_lds; A reg-staged fp32->bf16 (no separate convert kernel),
// 8 KB double-buffer, one barrier/k-step. 80 KB LDS -> 2 blocks/CU.

#define N_V   50000
#define KNB   16
#define D_F   256
#define H_F   256
#define HK2   512            // Y columns
#define NPAD  50048          // N rounded up to 128

typedef __bf16 bf16x8 __attribute__((ext_vector_type(8)));
typedef float  f32x4  __attribute__((ext_vector_type(4)));
typedef float  f32x8  __attribute__((ext_vector_type(8)));
typedef unsigned short ushort8 __attribute__((ext_vector_type(8)));

static __device__ __forceinline__ unsigned short f2bf(float f) {
    union { float f; unsigned u; } v; v.f = f;
    unsigned u = v.u;
    u += 0x7fffu + ((u >> 16) & 1u);   // round-to-nearest-even
    return (unsigned short)(u >> 16);
}
static __device__ __forceinline__ float bf2f(unsigned short u) {
    union { unsigned u; float f; } v; v.u = ((unsigned)u) << 16; return v.f;
}
static __device__ __forceinline__ void load16(const void* g, void* l) {
    __builtin_amdgcn_global_load_lds(
        (__attribute__((address_space(1))) void*)g,
        (__attribute__((address_space(3))) void*)l, 16, 0, 0);
}

// ---------------- kernel 1: W,B -> bf16 transposed WBt[512 h][256 k] ------
__global__ __launch_bounds__(256) void wbt_convert(
    const float* __restrict__ W, const float* __restrict__ Bm,
    unsigned short* __restrict__ WBt) {
    __shared__ unsigned short t[32][33];
    const int k0 = blockIdx.x * 32;                // 0..224
    const int h0 = blockIdx.y * 32;                // 0..480 (h<256:W, else B)
    const int tid = threadIdx.x;
    {
        int r  = tid >> 3;                         // k 0..31
        int c4 = (tid & 7) * 4;                    // h 0..28
        const float* src = (h0 < 256)
            ? (W  + (size_t)(k0 + r) * H_F + h0 + c4)
            : (Bm + (size_t)(k0 + r) * H_F + (h0 - 256) + c4);
        float4 v = *(const float4*)src;
        t[r][c4 + 0] = f2bf(v.x); t[r][c4 + 1] = f2bf(v.y);
        t[r][c4 + 2] = f2bf(v.z); t[r][c4 + 3] = f2bf(v.w);
    }
    __syncthreads();
    {
        int hh  = tid >> 3;
        int kk4 = (tid & 7) * 4;
        ushort4 o;
        o.x = t[kk4 + 0][hh]; o.y = t[kk4 + 1][hh];
        o.z = t[kk4 + 2][hh]; o.w = t[kk4 + 3][hh];
        *(ushort4*)(WBt + (size_t)(h0 + hh) * D_F + k0 + kk4) = o;
    }
}

// ---------------- kernel 2: Y = bf16(vf) @ WBt^T, 128x128 tile ------------
// B-panel [128 n][256 k] staged once, swizzle ((r&7)<<4) on 512-B rows.
// A [128 m][32 k] reg-staged from fp32 vf (cvt in-flight), dbuf 8 KB/buf,
// swizzle ((r&3)<<4) on 64-B rows.
// 8 waves: wm=wave&3 (32 rows), wn=wave>>2 (64 cols). 80 KB LDS, 2 blk/CU.
__global__ __launch_bounds__(512, 4) void gemm_y(
    const float* __restrict__ vf,
    const unsigned short* __restrict__ WBt,
    unsigned short* __restrict__ Y) {
    __shared__ char Bp[65536];
    __shared__ char Ap[2][8192];
    const int bn = blockIdx.x * 128;
    const int bm = blockIdx.y * 128;
    const int tid = threadIdx.x;
    const int wave = tid >> 6, lane = tid & 63;
    const int wm = wave & 3, wn = wave >> 2;

    f32x4 acc[2][4];
    const f32x4 fzero = {0.f, 0.f, 0.f, 0.f};
#pragma unroll
    for (int i = 0; i < 2; ++i)
#pragma unroll
        for (int j = 0; j < 4; ++j) acc[i][j] = fzero;

    // ---- stage B panel once: 64 KB = 8 x load16 per thread
#pragma unroll
    for (int i = 0; i < 8; ++i) {
        unsigned P = i * 8192u + tid * 16u;        // physical (linear dest)
        unsigned r = P >> 9, pc = P & 511u;
        unsigned lc = pc ^ ((r & 7u) << 4);        // logical byte col
        load16((const char*)WBt + (size_t)(bn + r) * 512 + lc,
               Bp + i * 8192 + wave * 1024);
    }

    // ---- A reg-staging: thread -> (row, 8 k-elems), fp32 load + cvt
    const int ar = tid >> 2;                       // 0..127
    const int ak = (tid & 3) * 8;                  // 0,8,16,24
    const int arow_g = (bm + ar < N_V) ? bm + ar : N_V - 1;   // clamp pad rows
    const float* aptr = vf + (size_t)arow_g * D_F + ak;
    const unsigned aOff = ar * 64u + (((unsigned)(ak * 2)) ^ (((unsigned)ar & 3u) << 4));
    float4 a0, a1;
    auto loadA = [&](int t) {
        a0 = *(const float4*)(aptr + t * 32);
        a1 = *(const float4*)(aptr + t * 32 + 4);
    };
    auto writeA = [&](int buf) {
        ushort8 o;
        o[0]=f2bf(a0.x); o[1]=f2bf(a0.y); o[2]=f2bf(a0.z); o[3]=f2bf(a0.w);
        o[4]=f2bf(a1.x); o[5]=f2bf(a1.y); o[6]=f2bf(a1.z); o[7]=f2bf(a1.w);
        *(ushort8*)(Ap[buf] + aOff) = o;
    };

    loadA(0);
    writeA(0);
    __syncthreads();                   // drains lgkm (A write) + vm (B panel)

    int cur = 0;
    for (int t = 0; t < 8; ++t) {
        if (t < 7) loadA(t + 1);       // fp32 loads in flight across compute
        bf16x8 af[2], bfr[4];
#pragma unroll
        for (int mf = 0; mf < 2; ++mf) {
            unsigned r = wm * 32u + mf * 16u + (lane & 15);
            unsigned c = ((unsigned)lane >> 4) << 4;
            af[mf] = *(const bf16x8*)(Ap[cur] + r * 64 + (c ^ ((r & 3u) << 4)));
        }
#pragma unroll
        for (int nf = 0; nf < 4; ++nf) {
            unsigned r = wn * 64u + nf * 16u + (lane & 15);
            unsigned c = t * 64u + (((unsigned)lane >> 4) << 4);
            bfr[nf] = *(const bf16x8*)(Bp + r * 512 + (c ^ ((r & 7u) << 4)));
        }
#pragma unroll
        for (int mf = 0; mf < 2; ++mf)
#pragma unroll
            for (int nf = 0; nf < 4; ++nf)
                acc[mf][nf] = __builtin_amdgcn_mfma_f32_16x16x32_bf16(
                    af[mf], bfr[nf], acc[mf][nf], 0, 0, 0);
        if (t < 7) writeA(cur ^ 1);    // waits vmcnt for a0/a1, writes other buf
        __syncthreads();               // A writes visible before next reads
        cur ^= 1;
    }

    // ---- epilogue: Y bf16 store (pad rows clamped-garbage, never read)
#pragma unroll
    for (int mf = 0; mf < 2; ++mf) {
        int row0 = bm + wm * 32 + mf * 16 + ((lane >> 4) << 2);
#pragma unroll
        for (int nf = 0; nf < 4; ++nf) {
            int col = bn + wn * 64 + nf * 16 + (lane & 15);
            f32x4 v = acc[mf][nf];
#pragma unroll
            for (int i = 0; i < 4; ++i)
                Y[(size_t)(row0 + i) * HK2 + col] = f2bf(v[i]);
        }
    }
}

// ---------------- kernel 3: gather + mean + add + relu, 2 verts/wave ------
__global__ __launch_bounds__(256) void gather_out(
    const unsigned short* __restrict__ Y, const int* __restrict__ nbr,
    const int* __restrict__ lens, float* __restrict__ out) {
    const int wave = threadIdx.x >> 6;
    const int lane = threadIdx.x & 63;
    const int half = lane >> 5, laneh = lane & 31;
    const int v = blockIdx.x * 8 + wave * 2 + half;   // 6250*8 == 50000 exact
    const int base = lane & 32;
    const int col = laneh * 8;

    const int len = lens[v];
    const int idx = nbr[(size_t)v * KNB + (laneh & 15)];
    const ushort8 y2 = *(const ushort8*)(Y + (size_t)v * HK2 + 256 + col);

    f32x8 acc = {0.f,0.f,0.f,0.f,0.f,0.f,0.f,0.f};
#define ROW_(j) (*(const ushort8*)(Y + (size_t)(j) * HK2 + col))
#define ACC_(r) { acc[0]+=bf2f(r[0]); acc[1]+=bf2f(r[1]); acc[2]+=bf2f(r[2]); \
                  acc[3]+=bf2f(r[3]); acc[4]+=bf2f(r[4]); acc[5]+=bf2f(r[5]); \
                  acc[6]+=bf2f(r[6]); acc[7]+=bf2f(r[7]); }
    int k = 0;
    for (; k + 4 <= len; k += 4) {
        int j0 = __shfl(idx, base + k),     j1 = __shfl(idx, base + k + 1);
        int j2 = __shfl(idx, base + k + 2), j3 = __shfl(idx, base + k + 3);
        ushort8 r0 = ROW_(j0), r1 = ROW_(j1), r2 = ROW_(j2), r3 = ROW_(j3);
        ACC_(r0); ACC_(r1); ACC_(r2); ACC_(r3);
    }
    for (; k < len; ++k) {
        int j = __shfl(idx, base + k);
        ushort8 r = ROW_(j);
        ACC_(r);
    }
#undef ROW_
#undef ACC_
    const float inv = 1.0f / (float)(len > 0 ? len : 1);
    float4 o0, o1;
    o0.x = fmaxf(fmaf(acc[0], inv, bf2f(y2[0])), 0.f);
    o0.y = fmaxf(fmaf(acc[1], inv, bf2f(y2[1])), 0.f);
    o0.z = fmaxf(fmaf(acc[2], inv, bf2f(y2[2])), 0.f);
    o0.w = fmaxf(fmaf(acc[3], inv, bf2f(y2[3])), 0.f);
    o1.x = fmaxf(fmaf(acc[4], inv, bf2f(y2[4])), 0.f);
    o1.y = fmaxf(fmaf(acc[5], inv, bf2f(y2[5])), 0.f);
    o1.z = fmaxf(fmaf(acc[6], inv, bf2f(y2[6])), 0.f);
    o1.w = fmaxf(fmaf(acc[7], inv, bf2f(y2[7])), 0.f);
    float* op = out + (size_t)v * H_F + col;
    *(float4*)op = o0;
    *(float4*)(op + 4) = o1;
}

extern "C" void kernel_launch(void* const* d_in, const int* in_sizes, int n_in,
                              void* d_out, int out_size, void* d_ws, size_t ws_size,
                              hipStream_t stream) {
    const float* vf   = (const float*)d_in[0];
    const int*   nbr  = (const int*)d_in[1];
    const int*   lens = (const int*)d_in[2];
    const float* W    = (const float*)d_in[3];
    const float* Bm   = (const float*)d_in[4];
    float* out = (float*)d_out;

    unsigned short* Y   = (unsigned short*)d_ws;                 // NPAD*512 bf16
    unsigned short* WBt = Y + (size_t)NPAD * HK2;                // 512*256 bf16

    hipLaunchKernelGGL(wbt_convert, dim3(8, 16), dim3(256), 0, stream, W, Bm, WBt);
    hipLaunchKernelGGL(gemm_y, dim3(4, NPAD / 128), dim3(512), 0, stream,
                       vf, WBt, Y);
    hipLaunchKernelGGL(gather_out, dim3(N_V / 8), dim3(256), 0, stream,
                       Y, nbr, lens, out);
}